// Round 9
// baseline (94.114 us; speedup 1.0000x reference)
//
#include <hip/hip_runtime.h>
#include <stdint.h>

#define D 512
#define KTOT 512        // plain fp16 GEMM: A=fp16(x), B=fp16(map)
#define BATCH 8192
#define NMAP 1024
#define GRID_W 32
#define ALPHA 0.5f
#define C2 15.859712f   // 2*(35.2*0.08)^2

typedef __attribute__((ext_vector_type(4))) float f32x4;
typedef __attribute__((ext_vector_type(8))) _Float16 f16x8;
typedef __attribute__((ext_vector_type(8))) unsigned short u16x8;

static __device__ __forceinline__ unsigned short f2h(float f) {
    union { _Float16 h; unsigned short u; } cv;
    cv.h = (_Float16)f;   // v_cvt_f16_f32, RTN, deterministic
    return cv.u;
}

// ---------------- prep: As=fp16(x), Bs=fp16(map), m2, packed-init ----------
__global__ __launch_bounds__(256) void k_prep(const float* __restrict__ x,
                                              const float* __restrict__ map,
                                              unsigned short* __restrict__ As,
                                              unsigned short* __restrict__ Bs,
                                              float* __restrict__ m2,
                                              unsigned long long* __restrict__ packed) {
    int bid = blockIdx.x;
    if (bid < BATCH * (D / 8) / 256) {
        // ---- x part: one thread per 8 elements ----
        int g = bid * 256 + threadIdx.x;
        if (g < BATCH) packed[g] = 0xFFFFFFFFFFFFFFFFull;
        int b = g >> 6;
        int k8 = (g & 63) << 3;
        const float* xp = x + (size_t)b * D + k8;
        float4 v0 = *(const float4*)xp;
        float4 v1 = *(const float4*)(xp + 4);
        float vv[8] = {v0.x, v0.y, v0.z, v0.w, v1.x, v1.y, v1.z, v1.w};
        u16x8 hi;
        #pragma unroll
        for (int j = 0; j < 8; j++) hi[j] = f2h(vv[j]);
        *(u16x8*)(As + (size_t)b * KTOT + k8) = hi;
    } else {
        // ---- map part: one wave per map row, 4 rows per block ----
        int mb = bid - BATCH * (D / 8) / 256;
        int n = mb * 4 + (threadIdx.x >> 6);
        int lane = threadIdx.x & 63;
        const float* mp = map + (size_t)n * D + lane * 8;
        float4 v0 = *(const float4*)mp;
        float4 v1 = *(const float4*)(mp + 4);
        float vv[8] = {v0.x, v0.y, v0.z, v0.w, v1.x, v1.y, v1.z, v1.w};
        u16x8 hi;
        float s = 0.f;
        #pragma unroll
        for (int j = 0; j < 8; j++) {
            s += vv[j] * vv[j];
            hi[j] = f2h(vv[j]);
        }
        *(u16x8*)(Bs + (size_t)n * KTOT + lane * 8) = hi;
        #pragma unroll
        for (int off = 32; off > 0; off >>= 1) s += __shfl_down(s, off);
        if (lane == 0) m2[n] = s;
    }
}

// ---------------- BMU: fp16 MFMA GEMM + fused argmin (2-phase dbuf) -------
// dist[b,n] = m2[n] - 2*dot(fp16(x[b]), fp16(map[n])); argmin_n per row b.
// 128x64 tile, BK=64, 4 waves (2x2, wave tile 64x32), 16x16x32 f16 MFMA.
// T3-minimum 2-phase: STAGE(t+1) issued BEFORE computing tile t; one
// __syncthreads() per tile (its vmcnt(0)+lgkmcnt(0) drain lands the
// prefetch that had the whole MFMA phase to fly). LDS 48 KB (2 bufs).
#define BM 128
#define BN 64
#define BK 64

__global__ __launch_bounds__(256) void k_bmu(const unsigned short* __restrict__ As,
                                             const unsigned short* __restrict__ Bs,
                                             const float* __restrict__ m2,
                                             unsigned long long* __restrict__ packed) {
    __shared__ unsigned short Al[2][BM * BK];  // 2 x 16 KB
    __shared__ unsigned short Bl[2][BN * BK];  // 2 x 8 KB
    const int xcd = blockIdx.x & 7;
    const int j = blockIdx.x >> 3;           // 0..127
    const int b0 = (xcd * 8 + (j & 7)) * BM; // b-tile within XCD's stripe
    const int n0 = (j >> 3) * BN;            // n-tile 0..15
    const int t = threadIdx.x;
    const int w = t >> 6, l = t & 63;
    const int wm = w >> 1, wn = w & 1;

    f32x4 acc[4][2];
    #pragma unroll
    for (int i = 0; i < 4; i++)
        #pragma unroll
        for (int jj = 0; jj < 2; jj++) acc[i][jj] = (f32x4)(0.f);

    const int srow = l >> 3;
    const int sslot = (l & 7) ^ (l >> 3);
    const unsigned short* agp0 = As + (size_t)(b0 + w * 32 + srow) * KTOT + sslot * 8;
    const unsigned short* bgp0 = Bs + (size_t)(n0 + w * 16 + srow) * KTOT + sslot * 8;

    #define STAGE(BUF, KT)                                                        \
    do {                                                                          \
        _Pragma("unroll")                                                         \
        for (int i = 0; i < 4; i++) {                                             \
            __builtin_amdgcn_global_load_lds(                                     \
                (const __attribute__((address_space(1))) void*)(agp0 + (size_t)i * 8 * KTOT + (KT)), \
                (__attribute__((address_space(3))) void*)(&Al[BUF][w * 2048 + i * 512]), 16, 0, 0); \
        }                                                                         \
        _Pragma("unroll")                                                         \
        for (int i = 0; i < 2; i++) {                                             \
            __builtin_amdgcn_global_load_lds(                                     \
                (const __attribute__((address_space(1))) void*)(bgp0 + (size_t)i * 8 * KTOT + (KT)), \
                (__attribute__((address_space(3))) void*)(&Bl[BUF][w * 1024 + i * 512]), 16, 0, 0); \
        }                                                                         \
    } while (0)

    STAGE(0, 0);
    __syncthreads();
    int cur = 0;
    for (int tt = 0; tt < KTOT / BK; ++tt) {
        if (tt < KTOT / BK - 1) STAGE(cur ^ 1, (tt + 1) * BK);
        #pragma unroll
        for (int kk = 0; kk < 2; kk++) {
            f16x8 af[4], bfr[2];
            #pragma unroll
            for (int mi = 0; mi < 4; mi++) {
                int r = wm * 64 + mi * 16 + (l & 15);
                int slot = kk * 4 + (l >> 4);
                af[mi] = *(const f16x8*)&Al[cur][r * 64 + ((slot ^ (r & 7)) << 3)];
            }
            #pragma unroll
            for (int nj = 0; nj < 2; nj++) {
                int r = wn * 32 + nj * 16 + (l & 15);
                int slot = kk * 4 + (l >> 4);
                bfr[nj] = *(const f16x8*)&Bl[cur][r * 64 + ((slot ^ (r & 7)) << 3)];
            }
            #pragma unroll
            for (int mi = 0; mi < 4; mi++)
                #pragma unroll
                for (int nj = 0; nj < 2; nj++)
                    acc[mi][nj] = __builtin_amdgcn_mfma_f32_16x16x32_f16(
                        af[mi], bfr[nj], acc[mi][nj], 0, 0, 0);
        }
        __syncthreads();   // drains vmcnt(0): prefetch landed; all reads done
        cur ^= 1;
    }
    #undef STAGE

    // ---- fused argmin epilogue ----
    float m2v[2];
    #pragma unroll
    for (int nj = 0; nj < 2; nj++)
        m2v[nj] = m2[n0 + wn * 32 + nj * 16 + (l & 15)];

    #pragma unroll
    for (int mi = 0; mi < 4; mi++) {
        #pragma unroll
        for (int reg = 0; reg < 4; reg++) {
            float best = m2v[0] - 2.0f * acc[mi][0][reg];
            int bi = n0 + wn * 32 + (l & 15);
            {
                float v = m2v[1] - 2.0f * acc[mi][1][reg];
                int n = n0 + wn * 32 + 16 + (l & 15);
                if (v < best) { best = v; bi = n; }
            }
            #pragma unroll
            for (int msk = 1; msk <= 8; msk <<= 1) {
                float ov = __shfl_xor(best, msk);
                int oi = __shfl_xor(bi, msk);
                if (ov < best || (ov == best && oi < bi)) { best = ov; bi = oi; }
            }
            if ((l & 15) == 0) {
                unsigned int fb = __float_as_uint(best);
                fb = (fb & 0x80000000u) ? ~fb : (fb | 0x80000000u);
                unsigned long long key =
                    ((unsigned long long)fb << 32) | (unsigned int)bi;
                int row = b0 + wm * 64 + mi * 16 + (l >> 4) * 4 + reg;
                atomicMin(&packed[row], key);
            }
        }
    }
}

// ---------------- deterministic scatter-sum (2-way ILP) ----------------
__global__ __launch_bounds__(256) void k_scatter(const float* __restrict__ x,
                                                 const unsigned long long* __restrict__ packed,
                                                 float* __restrict__ S,
                                                 int* __restrict__ cnt) {
    __shared__ int list[BATCH];
    __shared__ int cnts[256];
    __shared__ int offs[256];
    int g = blockIdx.x;
    int t = threadIdx.x;
    int b0 = t * (BATCH / 256);

    int mybmu[BATCH / 256];
    int c = 0;
    #pragma unroll
    for (int i = 0; i < BATCH / 256; i++) {
        mybmu[i] = (int)(packed[b0 + i] & 0xFFFFFFFFull);
        c += (mybmu[i] == g) ? 1 : 0;
    }
    cnts[t] = c;
    offs[t] = c;
    __syncthreads();
    #pragma unroll
    for (int s = 1; s < 256; s <<= 1) {
        int v = (t >= s) ? offs[t - s] : 0;
        __syncthreads();
        offs[t] += v;
        __syncthreads();
    }
    int off = offs[t] - cnts[t];
    #pragma unroll
    for (int i = 0; i < BATCH / 256; i++) {
        if (mybmu[i] == g) list[off++] = b0 + i;
    }
    __syncthreads();
    int len = offs[255];

    float a0 = 0.f, a1 = 0.f, c0 = 0.f, c1 = 0.f;
    int i = 0;
    for (; i + 2 <= len; i += 2) {
        const float* xr0 = x + (size_t)list[i] * D;
        const float* xr1 = x + (size_t)list[i + 1] * D;
        a0 += xr0[t]; a1 += xr0[t + 256];
        c0 += xr1[t]; c1 += xr1[t + 256];
    }
    if (i < len) {
        const float* xr = x + (size_t)list[i] * D;
        a0 += xr[t]; a1 += xr[t + 256];
    }
    S[(size_t)g * D + t] = a0 + c0;
    S[(size_t)g * D + t + 256] = a1 + c1;
    if (t == 0) cnt[g] = len;
}

// ---------------- separable conv axis j (+ sum_lr in block (0,0)) ----------
__global__ __launch_bounds__(256) void k_conv1(const float* __restrict__ S,
                                               float* __restrict__ V,
                                               const int* __restrict__ cnt,
                                               float* __restrict__ sum_lr) {
    __shared__ float tbl[GRID_W];
    __shared__ float vc[GRID_W][GRID_W];
    int gi = blockIdx.x;
    int d = blockIdx.y * 256 + threadIdx.x;
    if (threadIdx.x < GRID_W)
        tbl[threadIdx.x] = __expf(-(float)(threadIdx.x * threadIdx.x) / C2);
    __syncthreads();
    float acc[GRID_W];
    #pragma unroll
    for (int nj = 0; nj < GRID_W; nj++) acc[nj] = 0.f;
    for (int gj = 0; gj < GRID_W; gj++) {
        float s = S[(size_t)(gi * GRID_W + gj) * D + d];
        #pragma unroll
        for (int nj = 0; nj < GRID_W; nj++) {
            int dd = nj - gj; dd = dd < 0 ? -dd : dd;
            acc[nj] += tbl[dd] * s;
        }
    }
    #pragma unroll
    for (int nj = 0; nj < GRID_W; nj++)
        V[(size_t)(gi * GRID_W + nj) * D + d] = acc[nj];

    // ---- sum_lr (separable over counts), one block does it all ----
    if (blockIdx.x == 0 && blockIdx.y == 0) {
        int t = threadIdx.x;
        #pragma unroll
        for (int j = 0; j < 4; j++) {
            int idx = t * 4 + j;
            int a = idx >> 5, b = idx & 31;
            float s = 0.f;
            for (int gj = 0; gj < GRID_W; gj++) {
                int dd = gj - b; dd = dd < 0 ? -dd : dd;
                s += tbl[dd] * (float)cnt[a * GRID_W + gj];
            }
            vc[a][b] = s;
        }
        __syncthreads();
        #pragma unroll
        for (int j = 0; j < 4; j++) {
            int idx = t * 4 + j;
            int a = idx >> 5, b = idx & 31;
            float s2 = 0.f;
            for (int gg = 0; gg < GRID_W; gg++) {
                int dd = gg - a; dd = dd < 0 ? -dd : dd;
                s2 += tbl[dd] * vc[gg][b];
            }
            sum_lr[idx] = ALPHA * s2;
        }
    }
}

// ---------------- separable conv axis i + epilogue ----------------
__global__ __launch_bounds__(256) void k_conv2(const float* __restrict__ V,
                                               const float* __restrict__ map,
                                               const float* __restrict__ sum_lr,
                                               float* __restrict__ out) {
    __shared__ float tbl[GRID_W];
    int nj = blockIdx.x;
    int d = blockIdx.y * 256 + threadIdx.x;
    if (threadIdx.x < GRID_W)
        tbl[threadIdx.x] = __expf(-(float)(threadIdx.x * threadIdx.x) / C2);
    __syncthreads();
    float acc[GRID_W];
    #pragma unroll
    for (int ni = 0; ni < GRID_W; ni++) acc[ni] = 0.f;
    for (int gi = 0; gi < GRID_W; gi++) {
        float v = V[(size_t)(gi * GRID_W + nj) * D + d];
        #pragma unroll
        for (int ni = 0; ni < GRID_W; ni++) {
            int dd = ni - gi; dd = dd < 0 ? -dd : dd;
            acc[ni] += tbl[dd] * v;
        }
    }
    #pragma unroll
    for (int ni = 0; ni < GRID_W; ni++) {
        int n = ni * GRID_W + nj;
        out[(size_t)n * D + d] =
            map[(size_t)n * D + d] * (1.0f - sum_lr[n]) + ALPHA * acc[ni];
    }
}

// ---------------- launcher ----------------
extern "C" void kernel_launch(void* const* d_in, const int* in_sizes, int n_in,
                              void* d_out, int out_size, void* d_ws, size_t ws_size,
                              hipStream_t stream) {
    (void)in_sizes; (void)n_in; (void)out_size; (void)ws_size;
    const float* x = (const float*)d_in[0];
    const float* map = (const float*)d_in[1];
    float* out = (float*)d_out;

    char* ws = (char*)d_ws;
    unsigned long long* packed = (unsigned long long*)(ws);          // 64 KB
    float* m2 = (float*)(ws + 65536);                                // 4 KB
    int* cnt = (int*)(ws + 69632);                                   // 4 KB
    float* sum_lr = (float*)(ws + 73728);                            // 4 KB
    float* S = (float*)(ws + 77824);                                 // 2 MB
    float* V = (float*)(ws + 2174976);                               // 2 MB
    unsigned short* As = (unsigned short*)(ws + 4272128);            // 8 MB
    unsigned short* Bs = (unsigned short*)(ws + 12660736);           // 1 MB

    k_prep<<<BATCH * (D / 8) / 256 + NMAP / 4, 256, 0, stream>>>(x, map, As, Bs, m2, packed);
    k_bmu<<<(BATCH / BM) * (NMAP / BN), 256, 0, stream>>>(As, Bs, m2, packed);
    k_scatter<<<NMAP, 256, 0, stream>>>(x, packed, S, cnt);
    k_conv1<<<dim3(GRID_W, D / 256), 256, 0, stream>>>(S, V, cnt, sum_lr);
    k_conv2<<<dim3(GRID_W, D / 256), 256, 0, stream>>>(V, map, sum_lr, out);
}

// Round 10
// 91.308 us; speedup vs baseline: 1.0307x; 1.0307x over previous
//
#include <hip/hip_runtime.h>
#include <stdint.h>

#define D 512
#define KTOT 512        // plain fp16 GEMM: A=fp16(x), B=fp16(map)
#define BATCH 8192
#define NMAP 1024
#define GRID_W 32
#define ALPHA 0.5f
#define C2 15.859712f   // 2*(35.2*0.08)^2

typedef __attribute__((ext_vector_type(4))) float f32x4;
typedef __attribute__((ext_vector_type(8))) _Float16 f16x8;
typedef __attribute__((ext_vector_type(8))) unsigned short u16x8;

static __device__ __forceinline__ unsigned short f2h(float f) {
    union { _Float16 h; unsigned short u; } cv;
    cv.h = (_Float16)f;   // v_cvt_f16_f32, RTN, deterministic
    return cv.u;
}

// ---------------- prep: As=fp16(x), Bs=fp16(map), m2, packed-init ----------
__global__ __launch_bounds__(256) void k_prep(const float* __restrict__ x,
                                              const float* __restrict__ map,
                                              unsigned short* __restrict__ As,
                                              unsigned short* __restrict__ Bs,
                                              float* __restrict__ m2,
                                              unsigned long long* __restrict__ packed) {
    int bid = blockIdx.x;
    if (bid < BATCH * (D / 8) / 256) {
        // ---- x part: one thread per 8 elements ----
        int g = bid * 256 + threadIdx.x;
        if (g < BATCH) packed[g] = 0xFFFFFFFFFFFFFFFFull;
        int b = g >> 6;
        int k8 = (g & 63) << 3;
        const float* xp = x + (size_t)b * D + k8;
        float4 v0 = *(const float4*)xp;
        float4 v1 = *(const float4*)(xp + 4);
        float vv[8] = {v0.x, v0.y, v0.z, v0.w, v1.x, v1.y, v1.z, v1.w};
        u16x8 hi;
        #pragma unroll
        for (int j = 0; j < 8; j++) hi[j] = f2h(vv[j]);
        *(u16x8*)(As + (size_t)b * KTOT + k8) = hi;
    } else {
        // ---- map part: one wave per map row, 4 rows per block ----
        int mb = bid - BATCH * (D / 8) / 256;
        int n = mb * 4 + (threadIdx.x >> 6);
        int lane = threadIdx.x & 63;
        const float* mp = map + (size_t)n * D + lane * 8;
        float4 v0 = *(const float4*)mp;
        float4 v1 = *(const float4*)(mp + 4);
        float vv[8] = {v0.x, v0.y, v0.z, v0.w, v1.x, v1.y, v1.z, v1.w};
        u16x8 hi;
        float s = 0.f;
        #pragma unroll
        for (int j = 0; j < 8; j++) {
            s += vv[j] * vv[j];
            hi[j] = f2h(vv[j]);
        }
        *(u16x8*)(Bs + (size_t)n * KTOT + lane * 8) = hi;
        #pragma unroll
        for (int off = 32; off > 0; off >>= 1) s += __shfl_down(s, off);
        if (lane == 0) m2[n] = s;
    }
}

// ---------------- BMU: fp16 MFMA GEMM + fused argmin (R8 structure) -------
// dist[b,n] = m2[n] - 2*dot(fp16(x[b]), fp16(map[n])); argmin_n per row b.
// 128x64 tile, BK=64, 4 waves (2x2, wave tile 64x32), 16x16x32 f16 MFMA.
// Single-buffer; relies on ~4-6 resident blocks/CU for implicit overlap
// (m114) — explicit dbuf regressed (R9, replicating m99/m100).
#define BM 128
#define BN 64
#define BK 64

__global__ __launch_bounds__(256) void k_bmu(const unsigned short* __restrict__ As,
                                             const unsigned short* __restrict__ Bs,
                                             const float* __restrict__ m2,
                                             unsigned long long* __restrict__ packed) {
    __shared__ unsigned short Al[BM * BK];  // 16 KB
    __shared__ unsigned short Bl[BN * BK];  // 8 KB
    const int xcd = blockIdx.x & 7;
    const int j = blockIdx.x >> 3;           // 0..127
    const int b0 = (xcd * 8 + (j & 7)) * BM; // b-tile within XCD's stripe
    const int n0 = (j >> 3) * BN;            // n-tile 0..15
    const int t = threadIdx.x;
    const int w = t >> 6, l = t & 63;
    const int wm = w >> 1, wn = w & 1;

    f32x4 acc[4][2];
    #pragma unroll
    for (int i = 0; i < 4; i++)
        #pragma unroll
        for (int jj = 0; jj < 2; jj++) acc[i][jj] = (f32x4)(0.f);

    const int srow = l >> 3;
    const int sslot = (l & 7) ^ (l >> 3);
    const unsigned short* agp0 = As + (size_t)(b0 + w * 32 + srow) * KTOT + sslot * 8;
    const unsigned short* bgp0 = Bs + (size_t)(n0 + w * 16 + srow) * KTOT + sslot * 8;

    for (int kt = 0; kt < KTOT; kt += BK) {
        #pragma unroll
        for (int i = 0; i < 4; i++) {
            __builtin_amdgcn_global_load_lds(
                (const __attribute__((address_space(1))) void*)(agp0 + (size_t)i * 8 * KTOT + kt),
                (__attribute__((address_space(3))) void*)(Al + w * 2048 + i * 512), 16, 0, 0);
        }
        #pragma unroll
        for (int i = 0; i < 2; i++) {
            __builtin_amdgcn_global_load_lds(
                (const __attribute__((address_space(1))) void*)(bgp0 + (size_t)i * 8 * KTOT + kt),
                (__attribute__((address_space(3))) void*)(Bl + w * 1024 + i * 512), 16, 0, 0);
        }
        __syncthreads();

        #pragma unroll
        for (int kk = 0; kk < 2; kk++) {
            f16x8 af[4], bfr[2];
            #pragma unroll
            for (int mi = 0; mi < 4; mi++) {
                int r = wm * 64 + mi * 16 + (l & 15);
                int slot = kk * 4 + (l >> 4);
                af[mi] = *(const f16x8*)&Al[r * 64 + ((slot ^ (r & 7)) << 3)];
            }
            #pragma unroll
            for (int nj = 0; nj < 2; nj++) {
                int r = wn * 32 + nj * 16 + (l & 15);
                int slot = kk * 4 + (l >> 4);
                bfr[nj] = *(const f16x8*)&Bl[r * 64 + ((slot ^ (r & 7)) << 3)];
            }
            #pragma unroll
            for (int mi = 0; mi < 4; mi++)
                #pragma unroll
                for (int nj = 0; nj < 2; nj++)
                    acc[mi][nj] = __builtin_amdgcn_mfma_f32_16x16x32_f16(
                        af[mi], bfr[nj], acc[mi][nj], 0, 0, 0);
        }
        __syncthreads();
    }

    // ---- fused argmin epilogue ----
    float m2v[2];
    #pragma unroll
    for (int nj = 0; nj < 2; nj++)
        m2v[nj] = m2[n0 + wn * 32 + nj * 16 + (l & 15)];

    #pragma unroll
    for (int mi = 0; mi < 4; mi++) {
        #pragma unroll
        for (int reg = 0; reg < 4; reg++) {
            float best = m2v[0] - 2.0f * acc[mi][0][reg];
            int bi = n0 + wn * 32 + (l & 15);
            {
                float v = m2v[1] - 2.0f * acc[mi][1][reg];
                int n = n0 + wn * 32 + 16 + (l & 15);
                if (v < best) { best = v; bi = n; }
            }
            #pragma unroll
            for (int msk = 1; msk <= 8; msk <<= 1) {
                float ov = __shfl_xor(best, msk);
                int oi = __shfl_xor(bi, msk);
                if (ov < best || (ov == best && oi < bi)) { best = ov; bi = oi; }
            }
            if ((l & 15) == 0) {
                unsigned int fb = __float_as_uint(best);
                fb = (fb & 0x80000000u) ? ~fb : (fb | 0x80000000u);
                unsigned long long key =
                    ((unsigned long long)fb << 32) | (unsigned int)bi;
                int row = b0 + wm * 64 + mi * 16 + (l >> 4) * 4 + reg;
                atomicMin(&packed[row], key);
            }
        }
    }
}

// ---------------- deterministic scatter-sum (2-way ILP) ----------------
__global__ __launch_bounds__(256) void k_scatter(const float* __restrict__ x,
                                                 const unsigned long long* __restrict__ packed,
                                                 float* __restrict__ S,
                                                 int* __restrict__ cnt) {
    __shared__ int list[BATCH];
    __shared__ int cnts[256];
    __shared__ int offs[256];
    int g = blockIdx.x;
    int t = threadIdx.x;
    int b0 = t * (BATCH / 256);

    int mybmu[BATCH / 256];
    int c = 0;
    #pragma unroll
    for (int i = 0; i < BATCH / 256; i++) {
        mybmu[i] = (int)(packed[b0 + i] & 0xFFFFFFFFull);
        c += (mybmu[i] == g) ? 1 : 0;
    }
    cnts[t] = c;
    offs[t] = c;
    __syncthreads();
    #pragma unroll
    for (int s = 1; s < 256; s <<= 1) {
        int v = (t >= s) ? offs[t - s] : 0;
        __syncthreads();
        offs[t] += v;
        __syncthreads();
    }
    int off = offs[t] - cnts[t];
    #pragma unroll
    for (int i = 0; i < BATCH / 256; i++) {
        if (mybmu[i] == g) list[off++] = b0 + i;
    }
    __syncthreads();
    int len = offs[255];

    float a0 = 0.f, a1 = 0.f, c0 = 0.f, c1 = 0.f;
    int i = 0;
    for (; i + 2 <= len; i += 2) {
        const float* xr0 = x + (size_t)list[i] * D;
        const float* xr1 = x + (size_t)list[i + 1] * D;
        a0 += xr0[t]; a1 += xr0[t + 256];
        c0 += xr1[t]; c1 += xr1[t + 256];
    }
    if (i < len) {
        const float* xr = x + (size_t)list[i] * D;
        a0 += xr[t]; a1 += xr[t + 256];
    }
    S[(size_t)g * D + t] = a0 + c0;
    S[(size_t)g * D + t + 256] = a1 + c1;
    if (t == 0) cnt[g] = len;
}

// ---------------- separable conv axis j (+ sum_lr in block (0,0)) ----------
// 64-thread blocks, grid (32, 8): 256 blocks for latency hiding.
__global__ __launch_bounds__(64) void k_conv1(const float* __restrict__ S,
                                              float* __restrict__ V,
                                              const int* __restrict__ cnt,
                                              float* __restrict__ sum_lr) {
    __shared__ float tbl[GRID_W];
    __shared__ float vc[GRID_W][GRID_W];
    int gi = blockIdx.x;
    int d = blockIdx.y * 64 + threadIdx.x;
    if (threadIdx.x < GRID_W)
        tbl[threadIdx.x] = __expf(-(float)(threadIdx.x * threadIdx.x) / C2);
    __syncthreads();
    float acc[GRID_W];
    #pragma unroll
    for (int nj = 0; nj < GRID_W; nj++) acc[nj] = 0.f;
    for (int gj = 0; gj < GRID_W; gj++) {
        float s = S[(size_t)(gi * GRID_W + gj) * D + d];
        #pragma unroll
        for (int nj = 0; nj < GRID_W; nj++) {
            int dd = nj - gj; dd = dd < 0 ? -dd : dd;
            acc[nj] += tbl[dd] * s;
        }
    }
    #pragma unroll
    for (int nj = 0; nj < GRID_W; nj++)
        V[(size_t)(gi * GRID_W + nj) * D + d] = acc[nj];

    // ---- sum_lr (separable over counts), one block does it all ----
    if (blockIdx.x == 0 && blockIdx.y == 0) {
        int t = threadIdx.x;
        #pragma unroll
        for (int j = 0; j < 16; j++) {
            int idx = t * 16 + j;
            int a = idx >> 5, b = idx & 31;
            float s = 0.f;
            for (int gj = 0; gj < GRID_W; gj++) {
                int dd = gj - b; dd = dd < 0 ? -dd : dd;
                s += tbl[dd] * (float)cnt[a * GRID_W + gj];
            }
            vc[a][b] = s;
        }
        __syncthreads();
        #pragma unroll
        for (int j = 0; j < 16; j++) {
            int idx = t * 16 + j;
            int a = idx >> 5, b = idx & 31;
            float s2 = 0.f;
            for (int gg = 0; gg < GRID_W; gg++) {
                int dd = gg - a; dd = dd < 0 ? -dd : dd;
                s2 += tbl[dd] * vc[gg][b];
            }
            sum_lr[idx] = ALPHA * s2;
        }
    }
}

// ---------------- separable conv axis i + epilogue ----------------
__global__ __launch_bounds__(64) void k_conv2(const float* __restrict__ V,
                                              const float* __restrict__ map,
                                              const float* __restrict__ sum_lr,
                                              float* __restrict__ out) {
    __shared__ float tbl[GRID_W];
    int nj = blockIdx.x;
    int d = blockIdx.y * 64 + threadIdx.x;
    if (threadIdx.x < GRID_W)
        tbl[threadIdx.x] = __expf(-(float)(threadIdx.x * threadIdx.x) / C2);
    __syncthreads();
    float acc[GRID_W];
    #pragma unroll
    for (int ni = 0; ni < GRID_W; ni++) acc[ni] = 0.f;
    for (int gi = 0; gi < GRID_W; gi++) {
        float v = V[(size_t)(gi * GRID_W + nj) * D + d];
        #pragma unroll
        for (int ni = 0; ni < GRID_W; ni++) {
            int dd = ni - gi; dd = dd < 0 ? -dd : dd;
            acc[ni] += tbl[dd] * v;
        }
    }
    #pragma unroll
    for (int ni = 0; ni < GRID_W; ni++) {
        int n = ni * GRID_W + nj;
        out[(size_t)n * D + d] =
            map[(size_t)n * D + d] * (1.0f - sum_lr[n]) + ALPHA * acc[ni];
    }
}

// ---------------- launcher ----------------
extern "C" void kernel_launch(void* const* d_in, const int* in_sizes, int n_in,
                              void* d_out, int out_size, void* d_ws, size_t ws_size,
                              hipStream_t stream) {
    (void)in_sizes; (void)n_in; (void)out_size; (void)ws_size;
    const float* x = (const float*)d_in[0];
    const float* map = (const float*)d_in[1];
    float* out = (float*)d_out;

    char* ws = (char*)d_ws;
    unsigned long long* packed = (unsigned long long*)(ws);          // 64 KB
    float* m2 = (float*)(ws + 65536);                                // 4 KB
    int* cnt = (int*)(ws + 69632);                                   // 4 KB
    float* sum_lr = (float*)(ws + 73728);                            // 4 KB
    float* S = (float*)(ws + 77824);                                 // 2 MB
    float* V = (float*)(ws + 2174976);                               // 2 MB
    unsigned short* As = (unsigned short*)(ws + 4272128);            // 8 MB
    unsigned short* Bs = (unsigned short*)(ws + 12660736);           // 1 MB

    k_prep<<<BATCH * (D / 8) / 256 + NMAP / 4, 256, 0, stream>>>(x, map, As, Bs, m2, packed);
    k_bmu<<<(BATCH / BM) * (NMAP / BN), 256, 0, stream>>>(As, Bs, m2, packed);
    k_scatter<<<NMAP, 256, 0, stream>>>(x, packed, S, cnt);
    k_conv1<<<dim3(GRID_W, D / 64), 64, 0, stream>>>(S, V, cnt, sum_lr);
    k_conv2<<<dim3(GRID_W, D / 64), 64, 0, stream>>>(V, map, sum_lr, out);
}

// Round 11
// 83.262 us; speedup vs baseline: 1.1303x; 1.0966x over previous
//
#include <hip/hip_runtime.h>
#include <stdint.h>

#define D 512
#define KTOT 512        // plain fp16 GEMM: A=fp16(x), B=fp16(map)
#define BATCH 8192
#define NMAP 1024
#define GRID_W 32
#define ALPHA 0.5f
#define C2 15.859712f   // 2*(35.2*0.08)^2

typedef __attribute__((ext_vector_type(4))) float f32x4;
typedef __attribute__((ext_vector_type(8))) _Float16 f16x8;
typedef __attribute__((ext_vector_type(8))) unsigned short u16x8;

static __device__ __forceinline__ unsigned short f2h(float f) {
    union { _Float16 h; unsigned short u; } cv;
    cv.h = (_Float16)f;   // v_cvt_f16_f32, RTN, deterministic
    return cv.u;
}

// ---------------- prep: As=fp16(x), Bs=fp16(map), m2, packed-init ----------
__global__ __launch_bounds__(256) void k_prep(const float* __restrict__ x,
                                              const float* __restrict__ map,
                                              unsigned short* __restrict__ As,
                                              unsigned short* __restrict__ Bs,
                                              float* __restrict__ m2,
                                              unsigned long long* __restrict__ packed) {
    int bid = blockIdx.x;
    if (bid < BATCH * (D / 8) / 256) {
        // ---- x part: one thread per 8 elements ----
        int g = bid * 256 + threadIdx.x;
        if (g < BATCH) packed[g] = 0xFFFFFFFFFFFFFFFFull;
        int b = g >> 6;
        int k8 = (g & 63) << 3;
        const float* xp = x + (size_t)b * D + k8;
        float4 v0 = *(const float4*)xp;
        float4 v1 = *(const float4*)(xp + 4);
        float vv[8] = {v0.x, v0.y, v0.z, v0.w, v1.x, v1.y, v1.z, v1.w};
        u16x8 hi;
        #pragma unroll
        for (int j = 0; j < 8; j++) hi[j] = f2h(vv[j]);
        *(u16x8*)(As + (size_t)b * KTOT + k8) = hi;
    } else {
        // ---- map part: one wave per map row, 4 rows per block ----
        int mb = bid - BATCH * (D / 8) / 256;
        int n = mb * 4 + (threadIdx.x >> 6);
        int lane = threadIdx.x & 63;
        const float* mp = map + (size_t)n * D + lane * 8;
        float4 v0 = *(const float4*)mp;
        float4 v1 = *(const float4*)(mp + 4);
        float vv[8] = {v0.x, v0.y, v0.z, v0.w, v1.x, v1.y, v1.z, v1.w};
        u16x8 hi;
        float s = 0.f;
        #pragma unroll
        for (int j = 0; j < 8; j++) {
            s += vv[j] * vv[j];
            hi[j] = f2h(vv[j]);
        }
        *(u16x8*)(Bs + (size_t)n * KTOT + lane * 8) = hi;
        #pragma unroll
        for (int off = 32; off > 0; off >>= 1) s += __shfl_down(s, off);
        if (lane == 0) m2[n] = s;
    }
}

// ---------------- BMU: fp16 MFMA GEMM + fused argmin (R8 structure) -------
// dist[b,n] = m2[n] - 2*dot(fp16(x[b]), fp16(map[n])); argmin_n per row b.
// 128x64 tile, BK=64, 4 waves (2x2, wave tile 64x32), 16x16x32 f16 MFMA.
// Single-buffer; relies on ~4-6 resident blocks/CU for implicit overlap
// (m114) — explicit dbuf regressed (R9, replicating m99/m100).
#define BM 128
#define BN 64
#define BK 64

__global__ __launch_bounds__(256) void k_bmu(const unsigned short* __restrict__ As,
                                             const unsigned short* __restrict__ Bs,
                                             const float* __restrict__ m2,
                                             unsigned long long* __restrict__ packed) {
    __shared__ unsigned short Al[BM * BK];  // 16 KB
    __shared__ unsigned short Bl[BN * BK];  // 8 KB
    const int xcd = blockIdx.x & 7;
    const int j = blockIdx.x >> 3;           // 0..127
    const int b0 = (xcd * 8 + (j & 7)) * BM; // b-tile within XCD's stripe
    const int n0 = (j >> 3) * BN;            // n-tile 0..15
    const int t = threadIdx.x;
    const int w = t >> 6, l = t & 63;
    const int wm = w >> 1, wn = w & 1;

    f32x4 acc[4][2];
    #pragma unroll
    for (int i = 0; i < 4; i++)
        #pragma unroll
        for (int jj = 0; jj < 2; jj++) acc[i][jj] = (f32x4)(0.f);

    const int srow = l >> 3;
    const int sslot = (l & 7) ^ (l >> 3);
    const unsigned short* agp0 = As + (size_t)(b0 + w * 32 + srow) * KTOT + sslot * 8;
    const unsigned short* bgp0 = Bs + (size_t)(n0 + w * 16 + srow) * KTOT + sslot * 8;

    for (int kt = 0; kt < KTOT; kt += BK) {
        #pragma unroll
        for (int i = 0; i < 4; i++) {
            __builtin_amdgcn_global_load_lds(
                (const __attribute__((address_space(1))) void*)(agp0 + (size_t)i * 8 * KTOT + kt),
                (__attribute__((address_space(3))) void*)(Al + w * 2048 + i * 512), 16, 0, 0);
        }
        #pragma unroll
        for (int i = 0; i < 2; i++) {
            __builtin_amdgcn_global_load_lds(
                (const __attribute__((address_space(1))) void*)(bgp0 + (size_t)i * 8 * KTOT + kt),
                (__attribute__((address_space(3))) void*)(Bl + w * 1024 + i * 512), 16, 0, 0);
        }
        __syncthreads();

        #pragma unroll
        for (int kk = 0; kk < 2; kk++) {
            f16x8 af[4], bfr[2];
            #pragma unroll
            for (int mi = 0; mi < 4; mi++) {
                int r = wm * 64 + mi * 16 + (l & 15);
                int slot = kk * 4 + (l >> 4);
                af[mi] = *(const f16x8*)&Al[r * 64 + ((slot ^ (r & 7)) << 3)];
            }
            #pragma unroll
            for (int nj = 0; nj < 2; nj++) {
                int r = wn * 32 + nj * 16 + (l & 15);
                int slot = kk * 4 + (l >> 4);
                bfr[nj] = *(const f16x8*)&Bl[r * 64 + ((slot ^ (r & 7)) << 3)];
            }
            #pragma unroll
            for (int mi = 0; mi < 4; mi++)
                #pragma unroll
                for (int nj = 0; nj < 2; nj++)
                    acc[mi][nj] = __builtin_amdgcn_mfma_f32_16x16x32_f16(
                        af[mi], bfr[nj], acc[mi][nj], 0, 0, 0);
        }
        __syncthreads();
    }

    // ---- fused argmin epilogue ----
    float m2v[2];
    #pragma unroll
    for (int nj = 0; nj < 2; nj++)
        m2v[nj] = m2[n0 + wn * 32 + nj * 16 + (l & 15)];

    #pragma unroll
    for (int mi = 0; mi < 4; mi++) {
        #pragma unroll
        for (int reg = 0; reg < 4; reg++) {
            float best = m2v[0] - 2.0f * acc[mi][0][reg];
            int bi = n0 + wn * 32 + (l & 15);
            {
                float v = m2v[1] - 2.0f * acc[mi][1][reg];
                int n = n0 + wn * 32 + 16 + (l & 15);
                if (v < best) { best = v; bi = n; }
            }
            #pragma unroll
            for (int msk = 1; msk <= 8; msk <<= 1) {
                float ov = __shfl_xor(best, msk);
                int oi = __shfl_xor(bi, msk);
                if (ov < best || (ov == best && oi < bi)) { best = ov; bi = oi; }
            }
            if ((l & 15) == 0) {
                unsigned int fb = __float_as_uint(best);
                fb = (fb & 0x80000000u) ? ~fb : (fb | 0x80000000u);
                unsigned long long key =
                    ((unsigned long long)fb << 32) | (unsigned int)bi;
                int row = b0 + wm * 64 + mi * 16 + (l >> 4) * 4 + reg;
                atomicMin(&packed[row], key);
            }
        }
    }
}

// ---------------- deterministic scatter-sum (2-way ILP) ----------------
__global__ __launch_bounds__(256) void k_scatter(const float* __restrict__ x,
                                                 const unsigned long long* __restrict__ packed,
                                                 float* __restrict__ S,
                                                 int* __restrict__ cnt) {
    __shared__ int list[BATCH];
    __shared__ int cnts[256];
    __shared__ int offs[256];
    int g = blockIdx.x;
    int t = threadIdx.x;
    int b0 = t * (BATCH / 256);

    int mybmu[BATCH / 256];
    int c = 0;
    #pragma unroll
    for (int i = 0; i < BATCH / 256; i++) {
        mybmu[i] = (int)(packed[b0 + i] & 0xFFFFFFFFull);
        c += (mybmu[i] == g) ? 1 : 0;
    }
    cnts[t] = c;
    offs[t] = c;
    __syncthreads();
    #pragma unroll
    for (int s = 1; s < 256; s <<= 1) {
        int v = (t >= s) ? offs[t - s] : 0;
        __syncthreads();
        offs[t] += v;
        __syncthreads();
    }
    int off = offs[t] - cnts[t];
    #pragma unroll
    for (int i = 0; i < BATCH / 256; i++) {
        if (mybmu[i] == g) list[off++] = b0 + i;
    }
    __syncthreads();
    int len = offs[255];

    float a0 = 0.f, a1 = 0.f, c0 = 0.f, c1 = 0.f;
    int i = 0;
    for (; i + 2 <= len; i += 2) {
        const float* xr0 = x + (size_t)list[i] * D;
        const float* xr1 = x + (size_t)list[i + 1] * D;
        a0 += xr0[t]; a1 += xr0[t + 256];
        c0 += xr1[t]; c1 += xr1[t + 256];
    }
    if (i < len) {
        const float* xr = x + (size_t)list[i] * D;
        a0 += xr[t]; a1 += xr[t + 256];
    }
    S[(size_t)g * D + t] = a0 + c0;
    S[(size_t)g * D + t + 256] = a1 + c1;
    if (t == 0) cnt[g] = len;
}

// ---------------- separable conv axis j (+ sum_lr in block (0,0)) ----------
__global__ __launch_bounds__(256) void k_conv1(const float* __restrict__ S,
                                               float* __restrict__ V,
                                               const int* __restrict__ cnt,
                                               float* __restrict__ sum_lr) {
    __shared__ float tbl[GRID_W];
    __shared__ float vc[GRID_W][GRID_W];
    int gi = blockIdx.x;
    int d = blockIdx.y * 256 + threadIdx.x;
    if (threadIdx.x < GRID_W)
        tbl[threadIdx.x] = __expf(-(float)(threadIdx.x * threadIdx.x) / C2);
    __syncthreads();
    float acc[GRID_W];
    #pragma unroll
    for (int nj = 0; nj < GRID_W; nj++) acc[nj] = 0.f;
    for (int gj = 0; gj < GRID_W; gj++) {
        float s = S[(size_t)(gi * GRID_W + gj) * D + d];
        #pragma unroll
        for (int nj = 0; nj < GRID_W; nj++) {
            int dd = nj - gj; dd = dd < 0 ? -dd : dd;
            acc[nj] += tbl[dd] * s;
        }
    }
    #pragma unroll
    for (int nj = 0; nj < GRID_W; nj++)
        V[(size_t)(gi * GRID_W + nj) * D + d] = acc[nj];

    // ---- sum_lr (separable over counts), one block does it all ----
    if (blockIdx.x == 0 && blockIdx.y == 0) {
        int t = threadIdx.x;
        #pragma unroll
        for (int j = 0; j < 4; j++) {
            int idx = t * 4 + j;
            int a = idx >> 5, b = idx & 31;
            float s = 0.f;
            for (int gj = 0; gj < GRID_W; gj++) {
                int dd = gj - b; dd = dd < 0 ? -dd : dd;
                s += tbl[dd] * (float)cnt[a * GRID_W + gj];
            }
            vc[a][b] = s;
        }
        __syncthreads();
        #pragma unroll
        for (int j = 0; j < 4; j++) {
            int idx = t * 4 + j;
            int a = idx >> 5, b = idx & 31;
            float s2 = 0.f;
            for (int gg = 0; gg < GRID_W; gg++) {
                int dd = gg - a; dd = dd < 0 ? -dd : dd;
                s2 += tbl[dd] * vc[gg][b];
            }
            sum_lr[idx] = ALPHA * s2;
        }
    }
}

// ---------------- separable conv axis i + epilogue ----------------
__global__ __launch_bounds__(256) void k_conv2(const float* __restrict__ V,
                                               const float* __restrict__ map,
                                               const float* __restrict__ sum_lr,
                                               float* __restrict__ out) {
    __shared__ float tbl[GRID_W];
    int nj = blockIdx.x;
    int d = blockIdx.y * 256 + threadIdx.x;
    if (threadIdx.x < GRID_W)
        tbl[threadIdx.x] = __expf(-(float)(threadIdx.x * threadIdx.x) / C2);
    __syncthreads();
    float acc[GRID_W];
    #pragma unroll
    for (int ni = 0; ni < GRID_W; ni++) acc[ni] = 0.f;
    for (int gi = 0; gi < GRID_W; gi++) {
        float v = V[(size_t)(gi * GRID_W + nj) * D + d];
        #pragma unroll
        for (int ni = 0; ni < GRID_W; ni++) {
            int dd = ni - gi; dd = dd < 0 ? -dd : dd;
            acc[ni] += tbl[dd] * v;
        }
    }
    #pragma unroll
    for (int ni = 0; ni < GRID_W; ni++) {
        int n = ni * GRID_W + nj;
        out[(size_t)n * D + d] =
            map[(size_t)n * D + d] * (1.0f - sum_lr[n]) + ALPHA * acc[ni];
    }
}

// ---------------- launcher ----------------
extern "C" void kernel_launch(void* const* d_in, const int* in_sizes, int n_in,
                              void* d_out, int out_size, void* d_ws, size_t ws_size,
                              hipStream_t stream) {
    (void)in_sizes; (void)n_in; (void)out_size; (void)ws_size;
    const float* x = (const float*)d_in[0];
    const float* map = (const float*)d_in[1];
    float* out = (float*)d_out;

    char* ws = (char*)d_ws;
    unsigned long long* packed = (unsigned long long*)(ws);          // 64 KB
    float* m2 = (float*)(ws + 65536);                                // 4 KB
    int* cnt = (int*)(ws + 69632);                                   // 4 KB
    float* sum_lr = (float*)(ws + 73728);                            // 4 KB
    float* S = (float*)(ws + 77824);                                 // 2 MB
    float* V = (float*)(ws + 2174976);                               // 2 MB
    unsigned short* As = (unsigned short*)(ws + 4272128);            // 8 MB
    unsigned short* Bs = (unsigned short*)(ws + 12660736);           // 1 MB

    k_prep<<<BATCH * (D / 8) / 256 + NMAP / 4, 256, 0, stream>>>(x, map, As, Bs, m2, packed);
    k_bmu<<<(BATCH / BM) * (NMAP / BN), 256, 0, stream>>>(As, Bs, m2, packed);
    k_scatter<<<NMAP, 256, 0, stream>>>(x, packed, S, cnt);
    k_conv1<<<dim3(GRID_W, D / 256), 256, 0, stream>>>(S, V, cnt, sum_lr);
    k_conv2<<<dim3(GRID_W, D / 256), 256, 0, stream>>>(V, map, sum_lr, out);
}